// Round 2
// 668.486 us; speedup vs baseline: 1.0333x; 1.0333x over previous
//
#include <hip/hip_runtime.h>
#include <stdint.h>
#include <math.h>

#define NPC 16777216      // 4096*4096 pixels per channel
#define NF4 4194304       // NPC/4 float4s per channel

typedef float f32x4 __attribute__((ext_vector_type(4)));

struct ChScalars {
  int vmin1, vmax1;   // float bits, masked min/max of input (positives only)
  int vmin2, vmax2;   // float bits, masked min/max of eq (=255*c) from CLAHE
  int mean_nz, nzpos; // mean of nonzero bins; nz_cnt>0 flag
  int pad0, pad1;
};

// bin = clip(floor(x1*255),0,255) where x1 = mask? (cond? (x-vmin)/rng : 0) : x
__device__ __forceinline__ int binof(float x, int cond1, float vmin, float rng) {
  float t = (x > 0.0f) ? (cond1 ? (x - vmin) / rng : 0.0f) : x;
  float b = floorf(t * 255.0f);
  b = fminf(fmaxf(b, 0.0f), 255.0f);
  return (int)b;
}

__global__ __launch_bounds__(256) void k_init(ChScalars* S, unsigned* hist) {
  int g = blockIdx.x * 256 + threadIdx.x;   // grid = 256 blocks -> 65536 threads
  hist[g] = 0u;                             // 4*64*256 = 65536 bins
  if (g < 4) {
    S[g].vmin1 = 0x7FFFFFFF;  // +inf-ish init for positive-float-bits min
    S[g].vmax1 = 0;           // 0 bits; >0 iff any masked pixel
    S[g].vmin2 = 0x7FFFFFFF;
    S[g].vmax2 = 0x80000000;  // INT_MIN; eq>=0 so signed-int compare valid
    S[g].mean_nz = 0;
    S[g].nzpos = 0;
    S[g].pad0 = 0; S[g].pad1 = 0;
  }
}

__global__ __launch_bounds__(256) void k_minmax1(const float* __restrict__ X,
                                                 ChScalars* __restrict__ S) {
  const int ch = blockIdx.y;
  const float4* xp = reinterpret_cast<const float4*>(X) + (size_t)ch * NF4;
  const int g = blockIdx.x * 256 + threadIdx.x;   // 0..262143
  int mn = 0x7FFFFFFF, mx = 0;
  #pragma unroll
  for (int i = 0; i < 16; ++i) {
    float4 v = xp[(size_t)i * 262144 + g];
    if (v.x > 0.0f) { int b = __float_as_int(v.x); mn = min(mn, b); mx = max(mx, b); }
    if (v.y > 0.0f) { int b = __float_as_int(v.y); mn = min(mn, b); mx = max(mx, b); }
    if (v.z > 0.0f) { int b = __float_as_int(v.z); mn = min(mn, b); mx = max(mx, b); }
    if (v.w > 0.0f) { int b = __float_as_int(v.w); mn = min(mn, b); mx = max(mx, b); }
  }
  __shared__ int smn[256], smx[256];
  smn[threadIdx.x] = mn; smx[threadIdx.x] = mx;
  __syncthreads();
  for (int st = 128; st > 0; st >>= 1) {
    if (threadIdx.x < st) {
      smn[threadIdx.x] = min(smn[threadIdx.x], smn[threadIdx.x + st]);
      smx[threadIdx.x] = max(smx[threadIdx.x], smx[threadIdx.x + st]);
    }
    __syncthreads();
  }
  if (threadIdx.x == 0) {
    atomicMin(&S[ch].vmin1, smn[0]);
    atomicMax(&S[ch].vmax1, smx[0]);
  }
}

// Block = 256-wide x 64-high region inside one tile. LDS histogram then flush.
// Sweep REVERSED so the freshest L3 lines from k_minmax1's tail get reused first,
// and the pass ends at low addresses (which k_apply<false> reads first).
__global__ __launch_bounds__(256) void k_hist(const float* __restrict__ X,
                                              const ChScalars* __restrict__ S,
                                              unsigned* __restrict__ hist) {
  const int ch = blockIdx.z;
  __shared__ unsigned lh[256];
  lh[threadIdx.x] = 0u;
  __syncthreads();
  const ChScalars s = S[ch];
  const int cond1 = s.vmax1 > 0;
  const float vmin = __int_as_float(s.vmin1);
  const float rng = fmaxf(__int_as_float(s.vmax1) - vmin, 1e-12f);
  const int X0 = (15 - (int)blockIdx.x) << 8;
  const int Y0 = (63 - (int)blockIdx.y) << 6;
  const float4* xp = reinterpret_cast<const float4*>(X) + (size_t)ch * NF4;
  for (int i = 0; i < 16; ++i) {
    int fidx = i * 256 + threadIdx.x;
    int r = fidx >> 6, c4 = fidx & 63;
    float4 v = xp[(size_t)(Y0 + r) * 1024 + (X0 >> 2) + c4];
    atomicAdd(&lh[binof(v.x, cond1, vmin, rng)], 1u);
    atomicAdd(&lh[binof(v.y, cond1, vmin, rng)], 1u);
    atomicAdd(&lh[binof(v.z, cond1, vmin, rng)], 1u);
    atomicAdd(&lh[binof(v.w, cond1, vmin, rng)], 1u);
  }
  __syncthreads();
  const int tile = ((Y0 >> 9) << 3) + (X0 >> 9);
  atomicAdd(&hist[((ch << 6) + tile) * 256 + threadIdx.x], lh[threadIdx.x]);
}

// One block per (tile, channel). Fuses former k_stats: each block recomputes the
// channel-wide zero-count/mean (64*256 u32 loads, L2-hot, negligible), then does
// clip/redistribute/cumsum -> LUT. Tile-0 block publishes mean_nz/nzpos to S for k_apply.
__global__ __launch_bounds__(256) void k_lut(const unsigned* __restrict__ hist,
                                             ChScalars* __restrict__ S,
                                             float* __restrict__ lut) {
  const int ch = blockIdx.y, tile = blockIdx.x, b = threadIdx.x;
  // ---- channel stats (identical math to former k_stats) ----
  unsigned long long cnt = 0;
  for (int t = 0; t < 64; ++t) cnt += hist[((ch << 6) + t) * 256 + b];
  __shared__ unsigned long long sh64[256];
  __shared__ unsigned zc;
  if (b == 0) zc = (unsigned)cnt;
  sh64[b] = (b == 0) ? 0ULL : (unsigned long long)b * cnt;
  __syncthreads();
  for (int st = 128; st > 0; st >>= 1) {
    if (b < st) sh64[b] += sh64[b + st];
    __syncthreads();
  }
  const long long nz = 16777216LL - (long long)zc;
  const float sumf = (float)sh64[0];               // reference sums in f32
  const long long d = (nz < 1) ? 1 : nz;
  const int mean_nz = (int)floor((double)sumf / (double)d);
  const int nzpos = (nz > 0) ? 1 : 0;
  if (tile == 0 && b == 0) { S[ch].mean_nz = mean_nz; S[ch].nzpos = nzpos; }
  // ---- LUT build (unchanged math) ----
  const unsigned* hrow = hist + ((ch << 6) + tile) * 256;
  float h = (float)hrow[b];
  if (nzpos && mean_nz != 0) {          // zero pixels filled with mean_nz
    unsigned h0 = hrow[0];
    if (b == 0) h = 0.0f;
    if (b == mean_nz) h += (float)h0;
  }
  __shared__ float sh[256];
  sh[b] = fmaxf(h - 40960.0f, 0.0f);        // cl = 40.0*262144/256
  __syncthreads();
  for (int st = 128; st > 0; st >>= 1) {
    if (b < st) sh[b] += sh[b + st];
    __syncthreads();
  }
  const float excess = sh[0];
  __syncthreads();
  float hc = fminf(h, 40960.0f);
  float batch = floorf(excess / 256.0f);
  float residual = excess - batch * 256.0f;
  float step = fmaxf(floorf(256.0f / fmaxf(residual, 1.0f)), 1.0f);
  float fb = (float)b;
  float res_add = ((fmodf(fb, step) == 0.0f) && (floorf(fb / step) < residual)) ? 1.0f : 0.0f;
  sh[b] = hc + batch + res_add;
  __syncthreads();
  // inclusive scan (all partial sums are exact integers < 2^24 -> order-independent)
  for (int st = 1; st < 256; st <<= 1) {
    float v = (b >= st) ? sh[b - st] : 0.0f;
    __syncthreads();
    sh[b] += v;
    __syncthreads();
  }
  float l = rintf(sh[b] * (255.0f / 262144.0f));   // scale exactly representable
  lut[((ch << 6) + tile) * 256 + b] = fminf(fmaxf(l, 0.0f), 255.0f);
}

// WRITE=false: reduce min/max of eq (=255*c) over mask (monotone /255 done at read).
// WRITE=true : apply final masked normalize and store (nontemporal, reversed sweep).
// Key change: the 4 neighborhood LUTs are interleaved as float4 -> ONE ds_read_b128
// gather per pixel instead of 4 bank-conflicted ds_read_b32 gathers.
template <bool WRITE>
__global__ __launch_bounds__(256) void k_apply(const float* __restrict__ X,
                                               const ChScalars* __restrict__ Sin,
                                               const float* __restrict__ lut,
                                               ChScalars* __restrict__ Smut,
                                               float* __restrict__ out) {
  const int ch = blockIdx.z;
  const int bx = WRITE ? (15 - (int)blockIdx.x) : (int)blockIdx.x;
  const int by = WRITE ? (63 - (int)blockIdx.y) : (int)blockIdx.y;
  const int X0 = bx << 8, Y0 = by << 6;
  const ChScalars s = Sin[ch];
  const int cond1 = s.vmax1 > 0;
  const float vmin = __int_as_float(s.vmin1);
  const float rng = fmaxf(__int_as_float(s.vmax1) - vmin, 1e-12f);
  // tile neighborhood is uniform per block (256x64 region inside a half-tile)
  const int iy0 = (Y0 < 256) ? -1 : ((Y0 - 256) >> 9);
  const int ix0 = (X0 < 256) ? -1 : ((X0 - 256) >> 9);
  const int y0t = (iy0 < 0) ? 0 : iy0;
  const int y1t = (iy0 + 1 > 7) ? 7 : (iy0 + 1);
  const int x0t = (ix0 < 0) ? 0 : ix0;
  const int x1t = (ix0 + 1 > 7) ? 7 : (ix0 + 1);
  __shared__ f32x4 L4[256];              // interleaved {L00,L01,L10,L11}[bin]
  {
    const float* lc = lut + (size_t)(ch << 6) * 256;
    f32x4 Lv;
    Lv.x = lc[(y0t * 8 + x0t) * 256 + threadIdx.x];
    Lv.y = lc[(y0t * 8 + x1t) * 256 + threadIdx.x];
    Lv.z = lc[(y1t * 8 + x0t) * 256 + threadIdx.x];
    Lv.w = lc[(y1t * 8 + x1t) * 256 + threadIdx.x];
    L4[threadIdx.x] = Lv;
  }
  __syncthreads();
  // vmin2/vmax2 hold min/max of eq; /255 (monotone, correctly rounded) maps to c-range,
  // bit-identical to reducing on eq/255 per pixel.
  const float vmax2c = __int_as_float(s.vmax2) / 255.0f;
  const float vmin2c = __int_as_float(s.vmin2) / 255.0f;
  const int cond2 = (s.vmax1 > 0) && (vmax2c > 0.0f);
  const float rng2 = fmaxf(vmax2c - vmin2c, 1e-12f);
  const float LO = (float)(1.0 / 255.0);
  const float SC = (float)(1.0 - 1.0 / 255.0);
  // per-lane loop invariants: c4 = (i*256+tid)&63 = tid&63, so wx is i-invariant
  const int c4 = threadIdx.x & 63;
  const int r0 = threadIdx.x >> 6;
  float wxk[4], omwxk[4];
  #pragma unroll
  for (int k = 0; k < 4; ++k) {
    float fx = ((float)(X0 + (c4 << 2) + k) + 0.5f) / 512.0f - 0.5f;  // exact
    float w = fx - floorf(fx);
    wxk[k] = w;
    omwxk[k] = 1.0f - w;
  }
  const float4* xp = reinterpret_cast<const float4*>(X) + (size_t)ch * NF4;
  float* op = WRITE ? (out + (size_t)ch * NPC) : nullptr;
  int mn = 0x7FFFFFFF, mx = 0x80000000;
  for (int i = 0; i < 16; ++i) {
    const int y = Y0 + i * 4 + r0;
    const size_t f4i = (size_t)y * 1024 + (X0 >> 2) + c4;
    const float4 v = xp[f4i];
    const float fy = ((float)y + 0.5f) / 512.0f - 0.5f;   // exact
    const float wy = fy - floorf(fy);
    const float omwy = 1.0f - wy;
    float vv[4] = {v.x, v.y, v.z, v.w};
    float res[4];
    #pragma unroll
    for (int k = 0; k < 4; ++k) {
      float xv = vv[k];
      int xb = binof(xv, cond1, vmin, rng);
      int zero = (xb == 0);
      int f = (zero && s.nzpos) ? s.mean_nz : xb;
      f32x4 Lv = L4[f];                   // single ds_read_b128 gather
      float eq = Lv.x * omwy * omwxk[k]
               + Lv.y * omwy * wxk[k]
               + Lv.z * wy * omwxk[k]
               + Lv.w * wy * wxk[k];
      if (zero) eq = 0.0f;
      if (WRITE) {
        float cval = eq / 255.0f;
        float o;
        if (xv > 0.0f) o = cond2 ? ((cval - vmin2c) / rng2 * SC + LO) : LO;
        else o = cval;   // mask-false pixels: c (== 0)
        res[k] = o;
      } else {
        if (xv > 0.0f) {
          int bb = __float_as_int(eq);   // eq >= 0: signed-int order == float order
          mn = min(mn, bb);
          mx = max(mx, bb);
        }
      }
    }
    if (WRITE) {
      f32x4 o4 = {res[0], res[1], res[2], res[3]};
      // nontemporal: don't let the 256MB output stream evict X from L3 mid-pass
      __builtin_nontemporal_store(o4, reinterpret_cast<f32x4*>(op) + f4i);
    }
  }
  if (!WRITE) {
    __shared__ int smn[256], smx[256];
    smn[threadIdx.x] = mn; smx[threadIdx.x] = mx;
    __syncthreads();
    for (int st = 128; st > 0; st >>= 1) {
      if (threadIdx.x < st) {
        smn[threadIdx.x] = min(smn[threadIdx.x], smn[threadIdx.x + st]);
        smx[threadIdx.x] = max(smx[threadIdx.x], smx[threadIdx.x + st]);
      }
      __syncthreads();
    }
    if (threadIdx.x == 0) {
      atomicMin(&Smut[ch].vmin2, smn[0]);
      atomicMax(&Smut[ch].vmax2, smx[0]);
    }
  }
}

extern "C" void kernel_launch(void* const* d_in, const int* in_sizes, int n_in,
                              void* d_out, int out_size, void* d_ws, size_t ws_size,
                              hipStream_t stream) {
  const float* X = (const float*)d_in[0];
  float* out = (float*)d_out;
  char* ws = (char*)d_ws;
  ChScalars* S = (ChScalars*)ws;                       // 128 B
  unsigned* hist = (unsigned*)(ws + 256);              // 4*64*256 u32 = 256 KB
  float* lut = (float*)(ws + 256 + 65536 * 4);         // 4*64*256 f32 = 256 KB

  k_init<<<256, 256, 0, stream>>>(S, hist);
  k_minmax1<<<dim3(1024, 4, 1), 256, 0, stream>>>(X, S);
  k_hist<<<dim3(16, 64, 4), 256, 0, stream>>>(X, S, hist);
  k_lut<<<dim3(64, 4, 1), 256, 0, stream>>>(hist, S, lut);
  k_apply<false><<<dim3(16, 64, 4), 256, 0, stream>>>(X, S, lut, S, nullptr);
  k_apply<true><<<dim3(16, 64, 4), 256, 0, stream>>>(X, S, lut, S, out);
}